// Round 10
// baseline (3559.966 us; speedup 1.0000x reference)
//
#include <hip/hip_runtime.h>
#include <hip/hip_bf16.h>
#include <stdint.h>

#define SEQ     512
#define BATCH   32
#define TOKENS  16384   // BATCH*SEQ
#define EMB     1024
#define HEADS   16
#define DEPTH   4
#define K1      1536    // 3*F
#define H3      3072
#define MLPD    4096
#define CH      8192    // tokens per processing chunk (attn/qkv phase)
#define NCH     (TOKENS / CH)
#define CB      (CH / SEQ)   // batches per chunk = 16

typedef unsigned short u16;
typedef __attribute__((ext_vector_type(4))) float  f32x4;
typedef __attribute__((ext_vector_type(8))) short  s16x8;
typedef __attribute__((ext_vector_type(4))) u16    u16x4;

#define MFMA_16x16x32_BF16 __builtin_amdgcn_mfma_f32_16x16x32_bf16

__device__ __forceinline__ u16 f2bf(float f) {
  union { float f; uint32_t i; } c; c.f = f;
  uint32_t u = c.i;
  u += 0x7FFFu + ((u >> 16) & 1u);   // RNE
  return (u16)(u >> 16);
}
__device__ __forceinline__ void gll16(const void* g, void* l) {
  __builtin_amdgcn_global_load_lds(
      (const __attribute__((address_space(1))) uint32_t*)g,
      (__attribute__((address_space(3))) uint32_t*)l, 16, 0, 0);
}

// ---------------------------------------------------------------------------
// Diagnostic fill (used only when ws_size is insufficient)
// ---------------------------------------------------------------------------
__global__ __launch_bounds__(256)
void fill_kernel(float* __restrict__ out, int n) {
  int i = blockIdx.x * 256 + threadIdx.x;
  if (i < n) out[i] = 1.0e6f;
}

// ---------------------------------------------------------------------------
// Weight transpose + bf16 round:  W[K][N] f32  ->  Wt [N][K] bf16
// grid: (N/64, K/64), 256 threads
// ---------------------------------------------------------------------------
__global__ __launch_bounds__(256)
void wtrans_kernel(const float* __restrict__ W, u16* __restrict__ oHi,
                   int K, int N) {
  const int n0 = blockIdx.x * 64, k0 = blockIdx.y * 64;
  __shared__ float tile[64][65];
  const int t = threadIdx.x;
  const int tr = t >> 4, tc4 = (t & 15) * 4;
#pragma unroll
  for (int rr = 0; rr < 4; ++rr) {
    int r = tr + rr * 16;
    const float4 v = *(const float4*)&W[(size_t)(k0 + r) * N + n0 + tc4];
    tile[r][tc4 + 0] = v.x; tile[r][tc4 + 1] = v.y;
    tile[r][tc4 + 2] = v.z; tile[r][tc4 + 3] = v.w;
  }
  __syncthreads();
#pragma unroll
  for (int rr = 0; rr < 4; ++rr) {
    int n = tr + rr * 16;
    u16x4 vh;
#pragma unroll
    for (int j = 0; j < 4; ++j) vh[j] = f2bf(tile[tc4 + j][n]);
    size_t o = (size_t)(n0 + n) * K + k0 + tc4;
    *(u16x4*)&oHi[o] = vh;
  }
}

// ---------------------------------------------------------------------------
// Concat 3 feature streams -> bf16 [M][1536] (full tensor).
// ---------------------------------------------------------------------------
__global__ __launch_bounds__(256)
void concat_kernel(const float* __restrict__ i1, const float* __restrict__ i2,
                   const float* __restrict__ tf, u16* __restrict__ fHi) {
  size_t gid = (size_t)blockIdx.x * 256 + threadIdx.x;
  size_t e = gid * 4;
  int m = (int)(e / K1), c = (int)(e % K1);
  const float* src = (c < 512) ? i1 : ((c < 1024) ? i2 : tf);
  const float4 v = *(const float4*)&src[(size_t)m * 512 + (c & 511)];
  u16x4 vh;
  vh[0] = f2bf(v.x); vh[1] = f2bf(v.y); vh[2] = f2bf(v.z); vh[3] = f2bf(v.w);
  *(u16x4*)&fHi[(size_t)m * K1 + c] = vh;
}

// ---------------------------------------------------------------------------
// sincos positional embedding table [512][1024] f32
// ---------------------------------------------------------------------------
__global__ __launch_bounds__(256)
void pos_kernel(float* __restrict__ pos) {
  const int t = blockIdx.x;
#pragma unroll
  for (int p = 0; p < 2; ++p) {
    int d = threadIdx.x + p * 256;              // 0..511
    double omega = pow(10000.0, -(double)d / 512.0);
    double v = (double)t * omega;
    pos[(size_t)t * EMB + d]       = (float)sin(v);
    pos[(size_t)t * EMB + 512 + d] = (float)cos(v);
  }
}

// ---------------------------------------------------------------------------
// LayerNorm over 1024; one wave per row. OUTF=0: bf16 out, 1: f32 out.
// ---------------------------------------------------------------------------
template <int OUTF>
__global__ __launch_bounds__(256)
void ln_kernel(const float* __restrict__ x, const float* __restrict__ scale,
               const float* __restrict__ bias, u16* __restrict__ hHi,
               float* __restrict__ outF) {
  const int w = threadIdx.x >> 6, lane = threadIdx.x & 63;
  const int row = blockIdx.x * 4 + w;
  const float* xr = x + (size_t)row * EMB;
  float4 vv[4];
  float s = 0.f, s2 = 0.f;
#pragma unroll
  for (int j = 0; j < 4; ++j) {
    vv[j] = *(const float4*)&xr[j * 256 + lane * 4];
    s  += vv[j].x + vv[j].y + vv[j].z + vv[j].w;
    s2 += vv[j].x * vv[j].x + vv[j].y * vv[j].y + vv[j].z * vv[j].z + vv[j].w * vv[j].w;
  }
#pragma unroll
  for (int m = 1; m < 64; m <<= 1) {
    s  += __shfl_xor(s, m);
    s2 += __shfl_xor(s2, m);
  }
  const float mu = s * (1.f / EMB);
  const float var = s2 * (1.f / EMB) - mu * mu;
  const float rs = rsqrtf(var + 1e-6f);
#pragma unroll
  for (int j = 0; j < 4; ++j) {
    int c = j * 256 + lane * 4;
    const float4 sc = *(const float4*)&scale[c];
    const float4 bi = *(const float4*)&bias[c];
    float h0 = (vv[j].x - mu) * rs * sc.x + bi.x;
    float h1 = (vv[j].y - mu) * rs * sc.y + bi.y;
    float h2 = (vv[j].z - mu) * rs * sc.z + bi.z;
    float h3 = (vv[j].w - mu) * rs * sc.w + bi.w;
    size_t o = (size_t)row * EMB + c;
    if (OUTF) {
      *(float4*)&outF[o] = make_float4(h0, h1, h2, h3);
    } else {
      u16x4 vh;
      vh[0] = f2bf(h0); vh[1] = f2bf(h1); vh[2] = f2bf(h2); vh[3] = f2bf(h3);
      *(u16x4*)&hHi[o] = vh;
    }
  }
}

// ---------------------------------------------------------------------------
// 256x256-tile bf16 GEMM, 8 waves (2M x 4N), BK=64, 2x64KiB dbuf (128 KiB).
// m201-style phase schedule: per K-tile 4 phases (one C-quadrant each):
//   {stage 2 chunk-pairs (phases 0,1) ; 12 ds_read_b128 ; s_barrier ;
//    lgkmcnt(0)+sched_barrier ; setprio(1) ; 16 MFMA ; setprio(0) ; s_barrier}
// Tile boundary: vmcnt(0) (issued >=2 phases after covered loads -> cheap) +
// s_barrier. Staging targets the dbuf whose readers all finished before the
// boundary barrier (race-safe; uniform barrier flow).
// Swizzle: LDS slot g ^ (r&7) within a row's 8 granules -> 8 bank-start
// groups, 2-way aliasing = free. Same involution on pre-swizzled source.
// EPI: 0 = +bias +pos -> f32 (MLP-in); 1 = +bias -> bf16 (QKV);
//      2 = +bias +res -> f32 (proj); 3 = gelu -> bf16 (fc1);
//      4 = +res -> f32 (fc2 accumulate).
// Requires M%256==0, N%256==0, K%64==0.
// ---------------------------------------------------------------------------
template <int EPI>
__global__ __launch_bounds__(512, 2)
void gemm8_kernel(const u16* __restrict__ A, const u16* __restrict__ B,
                  int K, int N, const float* __restrict__ bias,
                  const float* __restrict__ extra, float* __restrict__ outF,
                  u16* __restrict__ outHi) {
  const int tid = threadIdx.x;              // 0..511
  const int lane = tid & 63, w = tid >> 6;  // 8 waves
  const int wm = w >> 2, wn = w & 3;        // 2 x 4
  const int bm = blockIdx.x * 256, bn = blockIdx.y * 256;
  const int l15 = lane & 15, g4 = lane >> 4;

  // dbuf d: A [256][64] u16 @ d*32768, B @ d*32768+16384. 128 KiB total.
  __shared__ u16 lds8[65536];

  f32x4 acc[8][4];
#pragma unroll
  for (int i = 0; i < 8; ++i)
#pragma unroll
    for (int j = 0; j < 4; ++j) acc[i][j] = f32x4{0.f, 0.f, 0.f, 0.f};

  // ---- staging setup: per array 2048 x 16B chunks (r=c>>3, g=c&7), source
  // granule sg = g ^ (r&7); thread covers c = tid + p*512, p=0..3.
  const u16* pA[4]; const u16* pB[4];
  int dA[4], dB[4];
#pragma unroll
  for (int p = 0; p < 4; ++p) {
    int c = tid + p * 512;
    int r = c >> 3, g = c & 7;
    int sg = g ^ (r & 7);
    pA[p] = A + (size_t)(bm + r) * K + sg * 8;
    pB[p] = B + (size_t)(bn + r) * K + sg * 8;
    dA[p] = c * 8;
    dB[p] = 16384 + c * 8;
  }

  // ---- ds_read offsets (u16 index), loop-invariant; quadrant adds
  // mh*4096 (A, 64 rows) / nh*2048 (B, 32 rows) - both preserve r&7.
  int aOff[2][4], bOff[2][2];
#pragma unroll
  for (int kh = 0; kh < 2; ++kh) {
#pragma unroll
    for (int mi = 0; mi < 4; ++mi) {
      int r = wm * 128 + mi * 16 + l15;
      aOff[kh][mi] = r * 64 + ((kh * 4 + g4) ^ (r & 7)) * 8;
    }
#pragma unroll
    for (int ni = 0; ni < 2; ++ni) {
      int r = wn * 64 + ni * 16 + l15;
      bOff[kh][ni] = 16384 + r * 64 + ((kh * 4 + g4) ^ (r & 7)) * 8;
    }
  }

  const int NT = K >> 6;
  // prologue: stage K-tile 0 into dbuf0 (8 gll16/thread)
#pragma unroll
  for (int p = 0; p < 4; ++p) {
    gll16(pA[p], &lds8[dA[p]]); gll16(pB[p], &lds8[16384 + tid * 8 + p * 4096]);
  }
  // NOTE: B dest must match dB[p] exactly; rewrite explicitly:
  // (the line above used an equivalent linear form; keep canonical below)
  // -- no-op: dB[p] = 16384 + (tid + p*512)*8 == 16384 + tid*8 + p*4096.
#pragma unroll
  for (int p = 0; p < 4; ++p) { pA[p] += 64; pB[p] += 64; }

  for (int t = 0; t < NT; ++t) {
    const int rb = (t & 1) * 32768;
    const int sb = ((t & 1) ^ 1) * 32768;
    asm volatile("s_waitcnt vmcnt(0)" ::: "memory");
    __builtin_amdgcn_s_barrier();
    __builtin_amdgcn_sched_barrier(0);
    const bool more = (t + 1 < NT);
#pragma unroll
    for (int q = 0; q < 4; ++q) {
      const int mh = q >> 1, nh = q & 1;
      if (q == 0 && more) {
        gll16(pA[0], &lds8[sb + dA[0]]); gll16(pB[0], &lds8[sb + dB[0]]);
        gll16(pA[1], &lds8[sb + dA[1]]); gll16(pB[1], &lds8[sb + dB[1]]);
        pA[0] += 64; pB[0] += 64; pA[1] += 64; pB[1] += 64;
      }
      if (q == 1 && more) {
        gll16(pA[2], &lds8[sb + dA[2]]); gll16(pB[2], &lds8[sb + dB[2]]);
        gll16(pA[3], &lds8[sb + dA[3]]); gll16(pB[3], &lds8[sb + dB[3]]);
        pA[2] += 64; pB[2] += 64; pA[3] += 64; pB[3] += 64;
      }
      s16x8 Af[2][4], Bf[2][2];
#pragma unroll
      for (int kh = 0; kh < 2; ++kh) {
#pragma unroll
        for (int mi = 0; mi < 4; ++mi)
          Af[kh][mi] = *(const s16x8*)&lds8[rb + mh * 4096 + aOff[kh][mi]];
#pragma unroll
        for (int ni = 0; ni < 2; ++ni)
          Bf[kh][ni] = *(const s16x8*)&lds8[rb + nh * 2048 + bOff[kh][ni]];
      }
      __builtin_amdgcn_s_barrier();                       // barrier1
      asm volatile("s_waitcnt lgkmcnt(0)" ::: "memory");
      __builtin_amdgcn_sched_barrier(0);                  // rule #18
      __builtin_amdgcn_s_setprio(1);
#pragma unroll
      for (int kh = 0; kh < 2; ++kh)
#pragma unroll
        for (int mi = 0; mi < 4; ++mi)
#pragma unroll
          for (int ni = 0; ni < 2; ++ni)
            acc[mh * 4 + mi][nh * 2 + ni] =
                MFMA_16x16x32_BF16(Af[kh][mi], Bf[kh][ni],
                                   acc[mh * 4 + mi][nh * 2 + ni], 0, 0, 0);
      __builtin_amdgcn_s_setprio(0);
      __builtin_amdgcn_s_barrier();                       // barrier2
    }
  }
  // ---- epilogue: C/D layout row=(lane>>4)*4+reg, col=lane&15 ----
#pragma unroll
  for (int fm = 0; fm < 8; ++fm) {
#pragma unroll
    for (int ni = 0; ni < 4; ++ni) {
      int gc = bn + wn * 64 + ni * 16 + l15;
      float bv = (EPI == 0 || EPI == 1 || EPI == 2) ? bias[gc] : 0.f;
#pragma unroll
      for (int r_ = 0; r_ < 4; ++r_) {
        int gr = bm + wm * 128 + fm * 16 + g4 * 4 + r_;
        float v = acc[fm][ni][r_] + bv;
        size_t o = (size_t)gr * N + gc;
        if (EPI == 0) {
          outF[o] = v + extra[(size_t)(gr & (SEQ - 1)) * EMB + gc];
        } else if (EPI == 1) {
          outHi[o] = f2bf(v);
        } else if (EPI == 2 || EPI == 4) {
          outF[o] = v + extra[o];
        } else {  // EPI == 3: tanh-approx GELU -> bf16
          float t3 = v + 0.044715f * v * v * v;
          float gl = 0.5f * v * (1.f + tanhf(0.7978845608028654f * t3));
          outHi[o] = f2bf(gl);
        }
      }
    }
  }
}

// ---------------------------------------------------------------------------
// Flash attention fwd, one CH-token chunk (CB batches). grid (SEQ/64, HEADS, CB),
// 256 thr = 4 waves, each wave owns 16 q-rows. qkv: bf16 [CH][3072] (q|k|v).
// ---------------------------------------------------------------------------
__global__ __launch_bounds__(256, 2)
void attn_kernel(const u16* __restrict__ qkv, u16* __restrict__ oHi) {
  const int qb = blockIdx.x, h = blockIdx.y, b = blockIdx.z;
  const int tid = threadIdx.x, lane = tid & 63, w = tid >> 6;
  const int l15 = lane & 15, g4 = lane >> 4;

  __shared__ u16 smem[2048 + 2560 + 2048];
  u16* Klds = smem;
  u16* VT   = smem + 2048;
  u16* Pw   = smem + 2048 + 2560 + w * 512;

  const int q0 = qb * 64 + w * 16;
  const size_t base = (size_t)b * SEQ * H3 + (size_t)h * 64;

  s16x8 qf0, qf1;
  {
    const u16* qp = qkv + base + (size_t)(q0 + l15) * H3 + g4 * 8;
    qf0 = *(const s16x8*)qp;
    qf1 = *(const s16x8*)(qp + 32);
  }

  f32x4 of[4];
#pragma unroll
  for (int n = 0; n < 4; ++n) of[n] = f32x4{0.f, 0.f, 0.f, 0.f};
  float mrow[4] = {-1e30f, -1e30f, -1e30f, -1e30f};
  float lrow[4] = {0.f, 0.f, 0.f, 0.f};

  for (int kt = 0; kt < SEQ; kt += 32) {
    {
      int r = tid >> 3;
      int jj = (tid & 7) ^ (r & 7);
      gll16(qkv + base + (size_t)(kt + r) * H3 + EMB + jj * 8, &Klds[tid * 8]);
    }
    {
      int key = tid >> 3, j = tid & 7;
      s16x8 v = *(const s16x8*)(qkv + base + (size_t)(kt + key) * H3 + 2 * EMB + j * 8);
#pragma unroll
      for (int i = 0; i < 8; ++i) VT[(j * 8 + i) * 40 + key] = (u16)v[i];
    }
    __syncthreads();
    const int key0 = l15, key1 = 16 + l15;
    s16x8 kf00 = *(const s16x8*)&Klds[key0 * 64 + (((0 + g4) ^ (key0 & 7)) * 8)];
    s16x8 kf01 = *(const s16x8*)&Klds[key0 * 64 + (((4 + g4) ^ (key0 & 7)) * 8)];
    s16x8 kf10 = *(const s16x8*)&Klds[key1 * 64 + (((0 + g4) ^ (key1 & 7)) * 8)];
    s16x8 kf11 = *(const s16x8*)&Klds[key1 * 64 + (((4 + g4) ^ (key1 & 7)) * 8)];
    f32x4 z = f32x4{0.f, 0.f, 0.f, 0.f};
    f32x4 s0 = MFMA_16x16x32_BF16(qf0, kf00, z, 0, 0, 0);
    s0 = MFMA_16x16x32_BF16(qf1, kf01, s0, 0, 0, 0);
    f32x4 s1 = MFMA_16x16x32_BF16(qf0, kf10, z, 0, 0, 0);
    s1 = MFMA_16x16x32_BF16(qf1, kf11, s1, 0, 0, 0);
#pragma unroll
    for (int r_ = 0; r_ < 4; ++r_) {
      float mx = fmaxf(s0[r_], s1[r_]);
      mx = fmaxf(mx, __shfl_xor(mx, 1));
      mx = fmaxf(mx, __shfl_xor(mx, 2));
      mx = fmaxf(mx, __shfl_xor(mx, 4));
      mx = fmaxf(mx, __shfl_xor(mx, 8));
      float mnew = fmaxf(mrow[r_], mx);
      float alpha = __expf((mrow[r_] - mnew) * 0.125f);
      mrow[r_] = mnew;
      float p0 = __expf((s0[r_] - mnew) * 0.125f);
      float p1 = __expf((s1[r_] - mnew) * 0.125f);
      float ts = p0 + p1;
      ts += __shfl_xor(ts, 1);
      ts += __shfl_xor(ts, 2);
      ts += __shfl_xor(ts, 4);
      ts += __shfl_xor(ts, 8);
      lrow[r_] = lrow[r_] * alpha + ts;
      of[0][r_] *= alpha; of[1][r_] *= alpha;
      of[2][r_] *= alpha; of[3][r_] *= alpha;
      int row = g4 * 4 + r_;
      int sw = (row >> 1) & 3;
      int c0 = (l15 >> 3) ^ sw;
      int c1 = (2 + (l15 >> 3)) ^ sw;
      Pw[(row * 4 + c0) * 8 + (l15 & 7)] = f2bf(p0);
      Pw[(row * 4 + c1) * 8 + (l15 & 7)] = f2bf(p1);
    }
    {
      int pchunk = (l15 << 2) | (g4 ^ ((l15 >> 1) & 3));
      s16x8 pf = *(const s16x8*)&Pw[pchunk * 8];
#pragma unroll
      for (int n = 0; n < 4; ++n) {
        s16x8 vf = *(const s16x8*)&VT[(n * 16 + l15) * 40 + g4 * 8];
        of[n] = MFMA_16x16x32_BF16(pf, vf, of[n], 0, 0, 0);
      }
    }
    __syncthreads();
  }
#pragma unroll
  for (int r_ = 0; r_ < 4; ++r_) {
    float inv = 1.f / lrow[r_];
    int qrow = q0 + g4 * 4 + r_;
    size_t ob = (size_t)(b * SEQ + qrow) * EMB + h * 64;
#pragma unroll
    for (int n = 0; n < 4; ++n)
      oHi[ob + n * 16 + l15] = f2bf(of[n][r_] * inv);
  }
}

// ---------------------------------------------------------------------------
extern "C" void kernel_launch(void* const* d_in, const int* in_sizes, int n_in,
                              void* d_out, int out_size, void* d_ws, size_t ws_size,
                              hipStream_t stream) {
  const float* image1     = (const float*)d_in[0];
  const float* image2     = (const float*)d_in[1];
  const float* text_feat  = (const float*)d_in[2];
  const float* mlp_kernel = (const float*)d_in[3];
  const float* mlp_bias   = (const float*)d_in[4];
  const float* ln1_scale  = (const float*)d_in[5];
  const float* ln1_bias   = (const float*)d_in[6];
  const float* qkv_kernel = (const float*)d_in[7];
  const float* qkv_bias   = (const float*)d_in[8];
  const float* proj_kernel= (const float*)d_in[9];
  const float* proj_bias  = (const float*)d_in[10];
  const float* ln2_scale  = (const float*)d_in[11];
  const float* ln2_bias   = (const float*)d_in[12];
  const float* fc1_kernel = (const float*)d_in[13];
  const float* fc2_kernel = (const float*)d_in[14];
  const float* lnf_scale  = (const float*)d_in[15];
  const float* lnf_bias   = (const float*)d_in[16];

  // ---- workspace layout (bytes), ~178 MiB total
  size_t off = 0;
  auto take = [&](size_t bytes) { size_t o = off; off += (bytes + 255) & ~(size_t)255; return o; };
  char* ws = (char*)d_ws;
  const size_t oX    = take((size_t)TOKENS * EMB * 4);            // 64 MiB residual f32
  const size_t oPos  = take((size_t)SEQ * EMB * 4);               //  2 MiB
  const size_t oSh   = take((size_t)TOKENS * EMB * 2);            // 32 MiB: attn-out | hFull (MLP)
  const size_t oBig  = take((size_t)CH * H3 * 2 + (size_t)CH * EMB * 2); // 64 MiB: feats(48) | qkv(48)+hChunk(16) | fc1half(64)
  const size_t oWbuf = take((size_t)16 * 1024 * 1024);            // 16 MiB weight slots
  if (off > ws_size) {  // diagnostic: absmax ~1e6 next round => ws too small
    fill_kernel<<<(out_size + 255) / 256, 256, 0, stream>>>((float*)d_out, out_size);
    return;
  }

  float* x   = (float*)(ws + oX);
  float* pos = (float*)(ws + oPos);
  u16* shrd  = (u16*)(ws + oSh);
  u16* oA    = shrd;                            // attention output (full), attn phase
  u16* hFull = shrd;                            // LN2 output (full), MLP phase
  u16* big   = (u16*)(ws + oBig);
  u16* hC    = big + (size_t)CH * H3;           // per-chunk LN1 out, tail 16 MiB of big
  u16* wbuf  = (u16*)(ws + oWbuf);
  u16* wq  = wbuf;                              // 6 MiB [3072][1024]
  u16* wp  = wbuf + (size_t)3 * 1024 * 1024;    // 2 MiB [1024][1024]
  u16* wf1 = wbuf;                              // 8 MiB [4096][1024]
  u16* wf2 = wbuf + (size_t)4 * 1024 * 1024;    // 4 MiB [1024][2048]
  u16* w1t = wbuf;                              // 3 MiB [1024][1536]

  pos_kernel<<<SEQ, 256, 0, stream>>>(pos);

  // ---- MLP-in: x = concat(feats) @ W1 + b + pos (gemm8, full M)
  wtrans_kernel<<<dim3(EMB / 64, K1 / 64), 256, 0, stream>>>(mlp_kernel, w1t, K1, EMB);
  concat_kernel<<<TOKENS * K1 / 1024, 256, 0, stream>>>(image1, image2, text_feat, big);
  gemm8_kernel<0><<<dim3(TOKENS / 256, EMB / 256), 512, 0, stream>>>(
      big, w1t, K1, EMB, mlp_bias, pos, x, nullptr);

  for (int i = 0; i < DEPTH; ++i) {
    // ---- attention: qkvT -> wq, projT -> wp
    wtrans_kernel<<<dim3(H3 / 64, EMB / 64), 256, 0, stream>>>(
        qkv_kernel + (size_t)i * EMB * H3, wq, EMB, H3);
    wtrans_kernel<<<dim3(EMB / 64, EMB / 64), 256, 0, stream>>>(
        proj_kernel + (size_t)i * EMB * EMB, wp, EMB, EMB);
    for (int c = 0; c < NCH; ++c) {
      float* xc = x + (size_t)c * CH * EMB;
      ln_kernel<0><<<CH / 4, 256, 0, stream>>>(xc, ln1_scale + i * EMB, ln1_bias + i * EMB,
                                               hC, nullptr);
      gemm8_kernel<1><<<dim3(CH / 256, H3 / 256), 512, 0, stream>>>(
          hC, wq, EMB, H3, qkv_bias + i * H3, nullptr, nullptr, big);
      attn_kernel<<<dim3(SEQ / 64, HEADS, CB), 256, 0, stream>>>(big, oA + (size_t)c * CH * EMB);
    }
    gemm8_kernel<2><<<dim3(TOKENS / 256, EMB / 256), 512, 0, stream>>>(
        oA, wp, EMB, EMB, proj_bias + i * EMB, x, x, nullptr);
    // ---- MLP: hFull = LN2(x) ONCE (before any fc2 accumulate touches x)
    ln_kernel<0><<<TOKENS / 4, 256, 0, stream>>>(x, ln2_scale + i * EMB, ln2_bias + i * EMB,
                                                 hFull, nullptr);
    wtrans_kernel<<<dim3(MLPD / 64, EMB / 64), 256, 0, stream>>>(
        fc1_kernel + (size_t)i * EMB * MLPD, wf1, EMB, MLPD);
    for (int nh = 0; nh < 2; ++nh) {
      wtrans_kernel<<<dim3(EMB / 64, 2048 / 64), 256, 0, stream>>>(
          fc2_kernel + (size_t)i * MLPD * EMB + (size_t)nh * 2048 * EMB, wf2, 2048, EMB);
      gemm8_kernel<3><<<dim3(TOKENS / 256, 2048 / 256), 512, 0, stream>>>(
          hFull, wf1 + (size_t)nh * 2048 * 1024, EMB, 2048, nullptr, nullptr, nullptr, big);
      gemm8_kernel<4><<<dim3(TOKENS / 256, EMB / 256), 512, 0, stream>>>(
          big, wf2, 2048, EMB, nullptr, x, x, nullptr);
    }
  }
  ln_kernel<1><<<TOKENS / 4, 256, 0, stream>>>(x, lnf_scale, lnf_bias,
                                               nullptr, (float*)d_out);
}

// Round 11
// 3274.971 us; speedup vs baseline: 1.0870x; 1.0870x over previous
//
#include <hip/hip_runtime.h>
#include <hip/hip_bf16.h>
#include <stdint.h>

#define SEQ     512
#define BATCH   32
#define TOKENS  16384   // BATCH*SEQ
#define EMB     1024
#define HEADS   16
#define DEPTH   4
#define K1      1536    // 3*F
#define H3      3072
#define MLPD    4096
#define CH      8192    // tokens per processing chunk
#define NCH     (TOKENS / CH)
#define CB      (CH / SEQ)   // batches per chunk = 16

typedef unsigned short u16;
typedef __attribute__((ext_vector_type(4))) float  f32x4;
typedef __attribute__((ext_vector_type(8))) short  s16x8;
typedef __attribute__((ext_vector_type(4))) u16    u16x4;

#define MFMA_16x16x32_BF16 __builtin_amdgcn_mfma_f32_16x16x32_bf16

__device__ __forceinline__ u16 f2bf(float f) {
  union { float f; uint32_t i; } c; c.f = f;
  uint32_t u = c.i;
  u += 0x7FFFu + ((u >> 16) & 1u);   // RNE
  return (u16)(u >> 16);
}
__device__ __forceinline__ void gll16(const void* g, void* l) {
  __builtin_amdgcn_global_load_lds(
      (const __attribute__((address_space(1))) uint32_t*)g,
      (__attribute__((address_space(3))) uint32_t*)l, 16, 0, 0);
}

// ---------------------------------------------------------------------------
__global__ __launch_bounds__(256)
void fill_kernel(float* __restrict__ out, int n) {
  int i = blockIdx.x * 256 + threadIdx.x;
  if (i < n) out[i] = 1.0e6f;
}

// ---------------------------------------------------------------------------
// Weight transpose + bf16 round:  W[K][N] f32  ->  Wt [N][K] bf16
// ---------------------------------------------------------------------------
__global__ __launch_bounds__(256)
void wtrans_kernel(const float* __restrict__ W, u16* __restrict__ oHi,
                   int K, int N) {
  const int n0 = blockIdx.x * 64, k0 = blockIdx.y * 64;
  __shared__ float tile[64][65];
  const int t = threadIdx.x;
  const int tr = t >> 4, tc4 = (t & 15) * 4;
#pragma unroll
  for (int rr = 0; rr < 4; ++rr) {
    int r = tr + rr * 16;
    const float4 v = *(const float4*)&W[(size_t)(k0 + r) * N + n0 + tc4];
    tile[r][tc4 + 0] = v.x; tile[r][tc4 + 1] = v.y;
    tile[r][tc4 + 2] = v.z; tile[r][tc4 + 3] = v.w;
  }
  __syncthreads();
#pragma unroll
  for (int rr = 0; rr < 4; ++rr) {
    int n = tr + rr * 16;
    u16x4 vh;
#pragma unroll
    for (int j = 0; j < 4; ++j) vh[j] = f2bf(tile[tc4 + j][n]);
    size_t o = (size_t)(n0 + n) * K + k0 + tc4;
    *(u16x4*)&oHi[o] = vh;
  }
}

// ---------------------------------------------------------------------------
// Concat 3 feature streams -> bf16 [CH][1536], one CH-token chunk.
// ---------------------------------------------------------------------------
__global__ __launch_bounds__(256)
void concat_kernel(const float* __restrict__ i1, const float* __restrict__ i2,
                   const float* __restrict__ tf, u16* __restrict__ fHi) {
  size_t gid = (size_t)blockIdx.x * 256 + threadIdx.x;
  size_t e = gid * 4;
  int m = (int)(e / K1), c = (int)(e % K1);
  const float* src = (c < 512) ? i1 : ((c < 1024) ? i2 : tf);
  const float4 v = *(const float4*)&src[(size_t)m * 512 + (c & 511)];
  u16x4 vh;
  vh[0] = f2bf(v.x); vh[1] = f2bf(v.y); vh[2] = f2bf(v.z); vh[3] = f2bf(v.w);
  *(u16x4*)&fHi[(size_t)m * K1 + c] = vh;
}

// ---------------------------------------------------------------------------
// sincos positional embedding table [512][1024] f32
// ---------------------------------------------------------------------------
__global__ __launch_bounds__(256)
void pos_kernel(float* __restrict__ pos) {
  const int t = blockIdx.x;
#pragma unroll
  for (int p = 0; p < 2; ++p) {
    int d = threadIdx.x + p * 256;              // 0..511
    double omega = pow(10000.0, -(double)d / 512.0);
    double v = (double)t * omega;
    pos[(size_t)t * EMB + d]       = (float)sin(v);
    pos[(size_t)t * EMB + 512 + d] = (float)cos(v);
  }
}

// ---------------------------------------------------------------------------
// LayerNorm over 1024; one wave per row. OUTF=0: bf16 out, 1: f32 out.
// ---------------------------------------------------------------------------
template <int OUTF>
__global__ __launch_bounds__(256)
void ln_kernel(const float* __restrict__ x, const float* __restrict__ scale,
               const float* __restrict__ bias, u16* __restrict__ hHi,
               float* __restrict__ outF) {
  const int w = threadIdx.x >> 6, lane = threadIdx.x & 63;
  const int row = blockIdx.x * 4 + w;
  const float* xr = x + (size_t)row * EMB;
  float4 vv[4];
  float s = 0.f, s2 = 0.f;
#pragma unroll
  for (int j = 0; j < 4; ++j) {
    vv[j] = *(const float4*)&xr[j * 256 + lane * 4];
    s  += vv[j].x + vv[j].y + vv[j].z + vv[j].w;
    s2 += vv[j].x * vv[j].x + vv[j].y * vv[j].y + vv[j].z * vv[j].z + vv[j].w * vv[j].w;
  }
#pragma unroll
  for (int m = 1; m < 64; m <<= 1) {
    s  += __shfl_xor(s, m);
    s2 += __shfl_xor(s2, m);
  }
  const float mu = s * (1.f / EMB);
  const float var = s2 * (1.f / EMB) - mu * mu;
  const float rs = rsqrtf(var + 1e-6f);
#pragma unroll
  for (int j = 0; j < 4; ++j) {
    int c = j * 256 + lane * 4;
    const float4 sc = *(const float4*)&scale[c];
    const float4 bi = *(const float4*)&bias[c];
    float h0 = (vv[j].x - mu) * rs * sc.x + bi.x;
    float h1 = (vv[j].y - mu) * rs * sc.y + bi.y;
    float h2 = (vv[j].z - mu) * rs * sc.z + bi.z;
    float h3 = (vv[j].w - mu) * rs * sc.w + bi.w;
    size_t o = (size_t)row * EMB + c;
    if (OUTF) {
      *(float4*)&outF[o] = make_float4(h0, h1, h2, h3);
    } else {
      u16x4 vh;
      vh[0] = f2bf(h0); vh[1] = f2bf(h1); vh[2] = f2bf(h2); vh[3] = f2bf(h3);
      *(u16x4*)&hHi[o] = vh;
    }
  }
}

// ---------------------------------------------------------------------------
// 128x128-tile bf16 GEMM, 2-phase dbuf, 32 KiB LDS, 4 waves. The measured-best
// per-FLOP structure (r5: 420 TF fc-class at 3-4 blocks/CU). launch_bounds
// (256,4): 4 blocks/CU resident (LDS allows 5).
// EPI: 0 = +bias +pos -> f32; 1 = +bias -> bf16; 2 = +bias +res -> f32;
//      3 = gelu -> bf16; 4 = +res -> f32.
// ---------------------------------------------------------------------------
template <int EPI>
__global__ __launch_bounds__(256, 4)
void gemm1_kernel(const u16* __restrict__ A, const u16* __restrict__ B,
                  int K, int N, const float* __restrict__ bias,
                  const float* __restrict__ extra, float* __restrict__ outF,
                  u16* __restrict__ outHi) {
  const int tid = threadIdx.x;
  const int lane = tid & 63;
  const int w = tid >> 6;
  const int wm = w >> 1, wn = w & 1;
  const int bm = blockIdx.x * 128, bn = blockIdx.y * 128;
  const int l15 = lane & 15, g4 = lane >> 4;

  __shared__ u16 lds[16384];

  f32x4 acc[4][4];
#pragma unroll
  for (int i = 0; i < 4; ++i)
#pragma unroll
    for (int j = 0; j < 4; ++j) acc[i][j] = f32x4{0.f, 0.f, 0.f, 0.f};

  auto stage = [&](int buf, int k0) {
#pragma unroll
    for (int p = 0; p < 2; ++p) {
      int c = p * 256 + tid;
      int r = c >> 2;
      int gg = (c & 3) ^ ((r >> 1) & 3);
      gll16(A + (size_t)(bm + r) * K + k0 + gg * 8, &lds[buf * 8192 + c * 8]);
      gll16(B + (size_t)(bn + r) * K + k0 + gg * 8, &lds[buf * 8192 + 4096 + c * 8]);
    }
  };

  const int nk = K >> 5;
  stage(0, 0);
  for (int kt = 0; kt < nk; ++kt) {
    const int cur = kt & 1;
    __syncthreads();
    if (kt + 1 < nk) stage(cur ^ 1, (kt + 1) * 32);
    s16x8 ah[4], bh[4];
#pragma unroll
    for (int mi = 0; mi < 4; ++mi) {
      int r = wm * 64 + mi * 16 + l15;
      int chunk = (r << 2) | (g4 ^ ((r >> 1) & 3));
      ah[mi] = *(const s16x8*)&lds[cur * 8192 + chunk * 8];
    }
#pragma unroll
    for (int ni = 0; ni < 4; ++ni) {
      int r = wn * 64 + ni * 16 + l15;
      int chunk = (r << 2) | (g4 ^ ((r >> 1) & 3));
      bh[ni] = *(const s16x8*)&lds[cur * 8192 + 4096 + chunk * 8];
    }
#pragma unroll
    for (int mi = 0; mi < 4; ++mi)
#pragma unroll
      for (int ni = 0; ni < 4; ++ni)
        acc[mi][ni] = MFMA_16x16x32_BF16(ah[mi], bh[ni], acc[mi][ni], 0, 0, 0);
  }
#pragma unroll
  for (int mi = 0; mi < 4; ++mi) {
#pragma unroll
    for (int ni = 0; ni < 4; ++ni) {
      int gc = bn + wn * 64 + ni * 16 + l15;
      float bv = (EPI == 0 || EPI == 1 || EPI == 2) ? bias[gc] : 0.f;
#pragma unroll
      for (int r_ = 0; r_ < 4; ++r_) {
        int gr = bm + wm * 64 + mi * 16 + g4 * 4 + r_;
        float v = acc[mi][ni][r_] + bv;
        size_t o = (size_t)gr * N + gc;
        if (EPI == 0) {
          outF[o] = v + extra[(size_t)(gr & (SEQ - 1)) * EMB + gc];
        } else if (EPI == 1) {
          outHi[o] = f2bf(v);
        } else if (EPI == 2 || EPI == 4) {
          outF[o] = v + extra[o];
        } else {
          float t3 = v + 0.044715f * v * v * v;
          float gl = 0.5f * v * (1.f + tanhf(0.7978845608028654f * t3));
          outHi[o] = f2bf(gl);
        }
      }
    }
  }
}

// ---------------------------------------------------------------------------
// 256x256-tile bf16 GEMM, 8 waves, BK=32, 2x32KiB dbuf (r8 form — best 256²
// variant measured). One __syncthreads per K-step; setprio around MFMA.
// Swizzle: slot g4 ^ ((r>>1)&3), 0 conflicts measured (r8).
// EPI: 1 = +bias -> bf16 (QKV); 2 = +bias +res -> f32 (proj).
// ---------------------------------------------------------------------------
template <int EPI>
__global__ __launch_bounds__(512, 2)
void gemm8_kernel(const u16* __restrict__ A, const u16* __restrict__ B,
                  int K, int N, const float* __restrict__ bias,
                  const float* __restrict__ extra, float* __restrict__ outF,
                  u16* __restrict__ outHi) {
  const int tid = threadIdx.x;              // 0..511
  const int lane = tid & 63, w = tid >> 6;  // 8 waves
  const int wm = w >> 2, wn = w & 3;        // 2 x 4
  const int bm = blockIdx.x * 256, bn = blockIdx.y * 256;
  const int l15 = lane & 15, g4 = lane >> 4;

  __shared__ u16 lds8[32768];

  f32x4 acc[8][4];
#pragma unroll
  for (int i = 0; i < 8; ++i)
#pragma unroll
    for (int j = 0; j < 4; ++j) acc[i][j] = f32x4{0.f, 0.f, 0.f, 0.f};

  const int c0 = tid, c1 = tid + 512;
  const int r0 = c0 >> 2, r1 = c1 >> 2;
  const int sg0 = (c0 & 3) ^ ((r0 >> 1) & 3);
  const int sg1 = (c1 & 3) ^ ((r1 >> 1) & 3);
  const u16* pA0 = A + (size_t)(bm + r0) * K + sg0 * 8;
  const u16* pA1 = A + (size_t)(bm + r1) * K + sg1 * 8;
  const u16* pB0 = B + (size_t)(bn + r0) * K + sg0 * 8;
  const u16* pB1 = B + (size_t)(bn + r1) * K + sg1 * 8;
  u16* dA0 = &lds8[c0 * 8];
  u16* dA1 = &lds8[c1 * 8];
  u16* dB0 = &lds8[8192 + c0 * 8];
  u16* dB1 = &lds8[8192 + c1 * 8];

  int aIdx[8], bIdx[4];
#pragma unroll
  for (int mi = 0; mi < 8; ++mi) {
    int r = wm * 128 + mi * 16 + l15;
    aIdx[mi] = ((r << 2) | (g4 ^ ((r >> 1) & 3))) * 8;
  }
#pragma unroll
  for (int ni = 0; ni < 4; ++ni) {
    int r = wn * 64 + ni * 16 + l15;
    bIdx[ni] = (((r << 2) | (g4 ^ ((r >> 1) & 3))) * 8) + 8192;
  }

  const int NK = K >> 5;
  gll16(pA0, dA0); gll16(pA1, dA1);
  gll16(pB0, dB0); gll16(pB1, dB1);
  pA0 += 32; pA1 += 32; pB0 += 32; pB1 += 32;
  __syncthreads();
  for (int kt = 0; kt < NK; ++kt) {
    const int ab = (kt & 1) * 16384;
    const int nb = ((kt & 1) ^ 1) * 16384;
    if (kt + 1 < NK) {
      gll16(pA0, dA0 + nb); gll16(pA1, dA1 + nb);
      gll16(pB0, dB0 + nb); gll16(pB1, dB1 + nb);
      pA0 += 32; pA1 += 32; pB0 += 32; pB1 += 32;
    }
    s16x8 Bf[4], Af[4];
#pragma unroll
    for (int ni = 0; ni < 4; ++ni)
      Bf[ni] = *(const s16x8*)&lds8[ab + bIdx[ni]];
#pragma unroll
    for (int mi = 0; mi < 4; ++mi)
      Af[mi] = *(const s16x8*)&lds8[ab + aIdx[mi]];
    __builtin_amdgcn_s_setprio(1);
#pragma unroll
    for (int mi = 0; mi < 4; ++mi)
#pragma unroll
      for (int ni = 0; ni < 4; ++ni)
        acc[mi][ni] = MFMA_16x16x32_BF16(Af[mi], Bf[ni], acc[mi][ni], 0, 0, 0);
    __builtin_amdgcn_s_setprio(0);
#pragma unroll
    for (int mi = 0; mi < 4; ++mi)
      Af[mi] = *(const s16x8*)&lds8[ab + aIdx[4 + mi]];
    __builtin_amdgcn_s_setprio(1);
#pragma unroll
    for (int mi = 0; mi < 4; ++mi)
#pragma unroll
      for (int ni = 0; ni < 4; ++ni)
        acc[4 + mi][ni] = MFMA_16x16x32_BF16(Af[mi], Bf[ni], acc[4 + mi][ni], 0, 0, 0);
    __builtin_amdgcn_s_setprio(0);
    __syncthreads();
  }
#pragma unroll
  for (int fm = 0; fm < 8; ++fm) {
#pragma unroll
    for (int ni = 0; ni < 4; ++ni) {
      int gc = bn + wn * 64 + ni * 16 + l15;
      float bv = (EPI == 1 || EPI == 2) ? bias[gc] : 0.f;
#pragma unroll
      for (int r_ = 0; r_ < 4; ++r_) {
        int gr = bm + wm * 128 + fm * 16 + g4 * 4 + r_;
        float v = acc[fm][ni][r_] + bv;
        size_t o = (size_t)gr * N + gc;
        if (EPI == 1) {
          outHi[o] = f2bf(v);
        } else {
          outF[o] = v + extra[o];
        }
      }
    }
  }
}

// ---------------------------------------------------------------------------
// Flash attention fwd, one CH-token chunk (CB batches). grid (SEQ/64, HEADS, CB).
// ---------------------------------------------------------------------------
__global__ __launch_bounds__(256, 2)
void attn_kernel(const u16* __restrict__ qkv, u16* __restrict__ oHi) {
  const int qb = blockIdx.x, h = blockIdx.y, b = blockIdx.z;
  const int tid = threadIdx.x, lane = tid & 63, w = tid >> 6;
  const int l15 = lane & 15, g4 = lane >> 4;

  __shared__ u16 smem[2048 + 2560 + 2048];
  u16* Klds = smem;
  u16* VT   = smem + 2048;
  u16* Pw   = smem + 2048 + 2560 + w * 512;

  const int q0 = qb * 64 + w * 16;
  const size_t base = (size_t)b * SEQ * H3 + (size_t)h * 64;

  s16x8 qf0, qf1;
  {
    const u16* qp = qkv + base + (size_t)(q0 + l15) * H3 + g4 * 8;
    qf0 = *(const s16x8*)qp;
    qf1 = *(const s16x8*)(qp + 32);
  }

  f32x4 of[4];
#pragma unroll
  for (int n = 0; n < 4; ++n) of[n] = f32x4{0.f, 0.f, 0.f, 0.f};
  float mrow[4] = {-1e30f, -1e30f, -1e30f, -1e30f};
  float lrow[4] = {0.f, 0.f, 0.f, 0.f};

  for (int kt = 0; kt < SEQ; kt += 32) {
    {
      int r = tid >> 3;
      int jj = (tid & 7) ^ (r & 7);
      gll16(qkv + base + (size_t)(kt + r) * H3 + EMB + jj * 8, &Klds[tid * 8]);
    }
    {
      int key = tid >> 3, j = tid & 7;
      s16x8 v = *(const s16x8*)(qkv + base + (size_t)(kt + key) * H3 + 2 * EMB + j * 8);
#pragma unroll
      for (int i = 0; i < 8; ++i) VT[(j * 8 + i) * 40 + key] = (u16)v[i];
    }
    __syncthreads();
    const int key0 = l15, key1 = 16 + l15;
    s16x8 kf00 = *(const s16x8*)&Klds[key0 * 64 + (((0 + g4) ^ (key0 & 7)) * 8)];
    s16x8 kf01 = *(const s16x8*)&Klds[key0 * 64 + (((4 + g4) ^ (key0 & 7)) * 8)];
    s16x8 kf10 = *(const s16x8*)&Klds[key1 * 64 + (((0 + g4) ^ (key1 & 7)) * 8)];
    s16x8 kf11 = *(const s16x8*)&Klds[key1 * 64 + (((4 + g4) ^ (key1 & 7)) * 8)];
    f32x4 z = f32x4{0.f, 0.f, 0.f, 0.f};
    f32x4 s0 = MFMA_16x16x32_BF16(qf0, kf00, z, 0, 0, 0);
    s0 = MFMA_16x16x32_BF16(qf1, kf01, s0, 0, 0, 0);
    f32x4 s1 = MFMA_16x16x32_BF16(qf0, kf10, z, 0, 0, 0);
    s1 = MFMA_16x16x32_BF16(qf1, kf11, s1, 0, 0, 0);
#pragma unroll
    for (int r_ = 0; r_ < 4; ++r_) {
      float mx = fmaxf(s0[r_], s1[r_]);
      mx = fmaxf(mx, __shfl_xor(mx, 1));
      mx = fmaxf(mx, __shfl_xor(mx, 2));
      mx = fmaxf(mx, __shfl_xor(mx, 4));
      mx = fmaxf(mx, __shfl_xor(mx, 8));
      float mnew = fmaxf(mrow[r_], mx);
      float alpha = __expf((mrow[r_] - mnew) * 0.125f);
      mrow[r_] = mnew;
      float p0 = __expf((s0[r_] - mnew) * 0.125f);
      float p1 = __expf((s1[r_] - mnew) * 0.125f);
      float ts = p0 + p1;
      ts += __shfl_xor(ts, 1);
      ts += __shfl_xor(ts, 2);
      ts += __shfl_xor(ts, 4);
      ts += __shfl_xor(ts, 8);
      lrow[r_] = lrow[r_] * alpha + ts;
      of[0][r_] *= alpha; of[1][r_] *= alpha;
      of[2][r_] *= alpha; of[3][r_] *= alpha;
      int row = g4 * 4 + r_;
      int sw = (row >> 1) & 3;
      int c0 = (l15 >> 3) ^ sw;
      int c1 = (2 + (l15 >> 3)) ^ sw;
      Pw[(row * 4 + c0) * 8 + (l15 & 7)] = f2bf(p0);
      Pw[(row * 4 + c1) * 8 + (l15 & 7)] = f2bf(p1);
    }
    {
      int pchunk = (l15 << 2) | (g4 ^ ((l15 >> 1) & 3));
      s16x8 pf = *(const s16x8*)&Pw[pchunk * 8];
#pragma unroll
      for (int n = 0; n < 4; ++n) {
        s16x8 vf = *(const s16x8*)&VT[(n * 16 + l15) * 40 + g4 * 8];
        of[n] = MFMA_16x16x32_BF16(pf, vf, of[n], 0, 0, 0);
      }
    }
    __syncthreads();
  }
#pragma unroll
  for (int r_ = 0; r_ < 4; ++r_) {
    float inv = 1.f / lrow[r_];
    int qrow = q0 + g4 * 4 + r_;
    size_t ob = (size_t)(b * SEQ + qrow) * EMB + h * 64;
#pragma unroll
    for (int n = 0; n < 4; ++n)
      oHi[ob + n * 16 + l15] = f2bf(of[n][r_] * inv);
  }
}

// ---------------------------------------------------------------------------
extern "C" void kernel_launch(void* const* d_in, const int* in_sizes, int n_in,
                              void* d_out, int out_size, void* d_ws, size_t ws_size,
                              hipStream_t stream) {
  const float* image1     = (const float*)d_in[0];
  const float* image2     = (const float*)d_in[1];
  const float* text_feat  = (const float*)d_in[2];
  const float* mlp_kernel = (const float*)d_in[3];
  const float* mlp_bias   = (const float*)d_in[4];
  const float* ln1_scale  = (const float*)d_in[5];
  const float* ln1_bias   = (const float*)d_in[6];
  const float* qkv_kernel = (const float*)d_in[7];
  const float* qkv_bias   = (const float*)d_in[8];
  const float* proj_kernel= (const float*)d_in[9];
  const float* proj_bias  = (const float*)d_in[10];
  const float* ln2_scale  = (const float*)d_in[11];
  const float* ln2_bias   = (const float*)d_in[12];
  const float* fc1_kernel = (const float*)d_in[13];
  const float* fc2_kernel = (const float*)d_in[14];
  const float* lnf_scale  = (const float*)d_in[15];
  const float* lnf_bias   = (const float*)d_in[16];

  // ---- workspace layout (bytes), ~178 MiB total
  size_t off = 0;
  auto take = [&](size_t bytes) { size_t o = off; off += (bytes + 255) & ~(size_t)255; return o; };
  char* ws = (char*)d_ws;
  const size_t oX    = take((size_t)TOKENS * EMB * 4);            // 64 MiB residual f32
  const size_t oPos  = take((size_t)SEQ * EMB * 4);               //  2 MiB
  const size_t oSh   = take((size_t)TOKENS * EMB * 2);            // 32 MiB: attn-out | hFull (MLP)
  const size_t oBig  = take((size_t)CH * MLPD * 2);               // 64 MiB: feats | qkv+hC | m-chunk
  const size_t oWbuf = take((size_t)16 * 1024 * 1024);            // 16 MiB weight slots
  if (off > ws_size) {  // diagnostic: absmax ~1e6 next round => ws too small
    fill_kernel<<<(out_size + 255) / 256, 256, 0, stream>>>((float*)d_out, out_size);
    return;
  }

  float* x   = (float*)(ws + oX);
  float* pos = (float*)(ws + oPos);
  u16* shrd  = (u16*)(ws + oSh);
  u16* oA    = shrd;                            // attention output (full), attn phase
  u16* hFull = shrd;                            // LN2 output (full), MLP phase
  u16* big   = (u16*)(ws + oBig);
  u16* hC    = big + (size_t)CH * H3;           // per-chunk LN1 out (attn phase tail)
  u16* wbuf  = (u16*)(ws + oWbuf);
  u16* wq  = wbuf;                              // 6 MiB [3072][1024]
  u16* wp  = wbuf + (size_t)3 * 1024 * 1024;    // 2 MiB [1024][1024]
  u16* wf1 = wbuf;                              // 8 MiB [4096][1024]
  u16* wf2 = wbuf + (size_t)4 * 1024 * 1024;    // 8 MiB [1024][4096]
  u16* w1t = wbuf;                              // 3 MiB [1024][1536]

  pos_kernel<<<SEQ, 256, 0, stream>>>(pos);

  // ---- MLP-in: x = concat(feats) @ W1 + b + pos (gemm1, chunked)
  wtrans_kernel<<<dim3(EMB / 64, K1 / 64), 256, 0, stream>>>(mlp_kernel, w1t, K1, EMB);
  for (int c = 0; c < NCH; ++c) {
    const size_t fo = (size_t)c * CH * 512;
    concat_kernel<<<CH * K1 / 1024, 256, 0, stream>>>(image1 + fo, image2 + fo, text_feat + fo, big);
    gemm1_kernel<0><<<dim3(CH / 128, EMB / 128), 256, 0, stream>>>(
        big, w1t, K1, EMB, mlp_bias, pos, x + (size_t)c * CH * EMB, nullptr);
  }

  for (int i = 0; i < DEPTH; ++i) {
    // ---- attention: qkvT -> wq, projT -> wp (gemm8, r8 config)
    wtrans_kernel<<<dim3(H3 / 64, EMB / 64), 256, 0, stream>>>(
        qkv_kernel + (size_t)i * EMB * H3, wq, EMB, H3);
    wtrans_kernel<<<dim3(EMB / 64, EMB / 64), 256, 0, stream>>>(
        proj_kernel + (size_t)i * EMB * EMB, wp, EMB, EMB);
    for (int c = 0; c < NCH; ++c) {
      float* xc = x + (size_t)c * CH * EMB;
      ln_kernel<0><<<CH / 4, 256, 0, stream>>>(xc, ln1_scale + i * EMB, ln1_bias + i * EMB,
                                               hC, nullptr);
      gemm8_kernel<1><<<dim3(CH / 256, H3 / 256), 512, 0, stream>>>(
          hC, wq, EMB, H3, qkv_bias + i * H3, nullptr, nullptr, big);
      attn_kernel<<<dim3(SEQ / 64, HEADS, CB), 256, 0, stream>>>(big, oA + (size_t)c * CH * EMB);
    }
    gemm8_kernel<2><<<dim3(TOKENS / 256, EMB / 256), 512, 0, stream>>>(
        oA, wp, EMB, EMB, proj_bias + i * EMB, x, x, nullptr);

    // ---- MLP: hFull = LN2(x) once; fc1 full-N + fc2 full-K per M-chunk (gemm1)
    ln_kernel<0><<<TOKENS / 4, 256, 0, stream>>>(x, ln2_scale + i * EMB, ln2_bias + i * EMB,
                                                 hFull, nullptr);
    wtrans_kernel<<<dim3(MLPD / 64, EMB / 64), 256, 0, stream>>>(
        fc1_kernel + (size_t)i * EMB * MLPD, wf1, EMB, MLPD);
    wtrans_kernel<<<dim3(EMB / 64, MLPD / 64), 256, 0, stream>>>(
        fc2_kernel + (size_t)i * MLPD * EMB, wf2, MLPD, EMB);
    for (int c = 0; c < NCH; ++c) {
      float* xc = x + (size_t)c * CH * EMB;
      gemm1_kernel<3><<<dim3(CH / 128, MLPD / 128), 256, 0, stream>>>(
          hFull + (size_t)c * CH * EMB, wf1, EMB, MLPD, nullptr, nullptr, nullptr, big);
      gemm1_kernel<4><<<dim3(CH / 128, EMB / 128), 256, 0, stream>>>(
          big, wf2, MLPD, EMB, nullptr, xc, xc, nullptr);
    }
  }
  ln_kernel<1><<<TOKENS / 4, 256, 0, stream>>>(x, lnf_scale, lnf_bias,
                                               nullptr, (float*)d_out);
}

// Round 12
// 3212.470 us; speedup vs baseline: 1.1082x; 1.0195x over previous
//
#include <hip/hip_runtime.h>
#include <hip/hip_bf16.h>
#include <stdint.h>

#define SEQ     512
#define BATCH   32
#define TOKENS  16384   // BATCH*SEQ
#define EMB     1024
#define HEADS   16
#define DEPTH   4
#define K1      1536    // 3*F
#define H3      3072
#define MLPD    4096
#define CH      8192    // tokens per processing chunk
#define NCH     (TOKENS / CH)
#define CB      (CH / SEQ)   // batches per chunk = 16

typedef unsigned short u16;
typedef __attribute__((ext_vector_type(4))) float  f32x4;
typedef __attribute__((ext_vector_type(8))) short  s16x8;
typedef __attribute__((ext_vector_type(4))) u16    u16x4;

#define MFMA_16x16x32_BF16 __builtin_amdgcn_mfma_f32_16x16x32_bf16

__device__ __forceinline__ u16 f2bf(float f) {
  union { float f; uint32_t i; } c; c.f = f;
  uint32_t u = c.i;
  u += 0x7FFFu + ((u >> 16) & 1u);   // RNE
  return (u16)(u >> 16);
}
__device__ __forceinline__ void gll16(const void* g, void* l) {
  __builtin_amdgcn_global_load_lds(
      (const __attribute__((address_space(1))) uint32_t*)g,
      (__attribute__((address_space(3))) uint32_t*)l, 16, 0, 0);
}

// ---------------------------------------------------------------------------
__global__ __launch_bounds__(256)
void fill_kernel(float* __restrict__ out, int n) {
  int i = blockIdx.x * 256 + threadIdx.x;
  if (i < n) out[i] = 1.0e6f;
}

// ---------------------------------------------------------------------------
// Weight transpose + bf16 round:  W[K][N] f32  ->  Wt [N][K] bf16
// ---------------------------------------------------------------------------
__global__ __launch_bounds__(256)
void wtrans_kernel(const float* __restrict__ W, u16* __restrict__ oHi,
                   int K, int N) {
  const int n0 = blockIdx.x * 64, k0 = blockIdx.y * 64;
  __shared__ float tile[64][65];
  const int t = threadIdx.x;
  const int tr = t >> 4, tc4 = (t & 15) * 4;
#pragma unroll
  for (int rr = 0; rr < 4; ++rr) {
    int r = tr + rr * 16;
    const float4 v = *(const float4*)&W[(size_t)(k0 + r) * N + n0 + tc4];
    tile[r][tc4 + 0] = v.x; tile[r][tc4 + 1] = v.y;
    tile[r][tc4 + 2] = v.z; tile[r][tc4 + 3] = v.w;
  }
  __syncthreads();
#pragma unroll
  for (int rr = 0; rr < 4; ++rr) {
    int n = tr + rr * 16;
    u16x4 vh;
#pragma unroll
    for (int j = 0; j < 4; ++j) vh[j] = f2bf(tile[tc4 + j][n]);
    size_t o = (size_t)(n0 + n) * K + k0 + tc4;
    *(u16x4*)&oHi[o] = vh;
  }
}

// ---------------------------------------------------------------------------
// Concat 3 feature streams -> bf16 [CH][1536], one CH-token chunk.
// ---------------------------------------------------------------------------
__global__ __launch_bounds__(256)
void concat_kernel(const float* __restrict__ i1, const float* __restrict__ i2,
                   const float* __restrict__ tf, u16* __restrict__ fHi) {
  size_t gid = (size_t)blockIdx.x * 256 + threadIdx.x;
  size_t e = gid * 4;
  int m = (int)(e / K1), c = (int)(e % K1);
  const float* src = (c < 512) ? i1 : ((c < 1024) ? i2 : tf);
  const float4 v = *(const float4*)&src[(size_t)m * 512 + (c & 511)];
  u16x4 vh;
  vh[0] = f2bf(v.x); vh[1] = f2bf(v.y); vh[2] = f2bf(v.z); vh[3] = f2bf(v.w);
  *(u16x4*)&fHi[(size_t)m * K1 + c] = vh;
}

// ---------------------------------------------------------------------------
// sincos positional embedding table [512][1024] f32
// ---------------------------------------------------------------------------
__global__ __launch_bounds__(256)
void pos_kernel(float* __restrict__ pos) {
  const int t = blockIdx.x;
#pragma unroll
  for (int p = 0; p < 2; ++p) {
    int d = threadIdx.x + p * 256;              // 0..511
    double omega = pow(10000.0, -(double)d / 512.0);
    double v = (double)t * omega;
    pos[(size_t)t * EMB + d]       = (float)sin(v);
    pos[(size_t)t * EMB + 512 + d] = (float)cos(v);
  }
}

// ---------------------------------------------------------------------------
// LayerNorm over 1024; one wave per row. OUTF=0: bf16 out, 1: f32 out.
// ---------------------------------------------------------------------------
template <int OUTF>
__global__ __launch_bounds__(256)
void ln_kernel(const float* __restrict__ x, const float* __restrict__ scale,
               const float* __restrict__ bias, u16* __restrict__ hHi,
               float* __restrict__ outF) {
  const int w = threadIdx.x >> 6, lane = threadIdx.x & 63;
  const int row = blockIdx.x * 4 + w;
  const float* xr = x + (size_t)row * EMB;
  float4 vv[4];
  float s = 0.f, s2 = 0.f;
#pragma unroll
  for (int j = 0; j < 4; ++j) {
    vv[j] = *(const float4*)&xr[j * 256 + lane * 4];
    s  += vv[j].x + vv[j].y + vv[j].z + vv[j].w;
    s2 += vv[j].x * vv[j].x + vv[j].y * vv[j].y + vv[j].z * vv[j].z + vv[j].w * vv[j].w;
  }
#pragma unroll
  for (int m = 1; m < 64; m <<= 1) {
    s  += __shfl_xor(s, m);
    s2 += __shfl_xor(s2, m);
  }
  const float mu = s * (1.f / EMB);
  const float var = s2 * (1.f / EMB) - mu * mu;
  const float rs = rsqrtf(var + 1e-6f);
#pragma unroll
  for (int j = 0; j < 4; ++j) {
    int c = j * 256 + lane * 4;
    const float4 sc = *(const float4*)&scale[c];
    const float4 bi = *(const float4*)&bias[c];
    float h0 = (vv[j].x - mu) * rs * sc.x + bi.x;
    float h1 = (vv[j].y - mu) * rs * sc.y + bi.y;
    float h2 = (vv[j].z - mu) * rs * sc.z + bi.z;
    float h3 = (vv[j].w - mu) * rs * sc.w + bi.w;
    size_t o = (size_t)row * EMB + c;
    if (OUTF) {
      *(float4*)&outF[o] = make_float4(h0, h1, h2, h3);
    } else {
      u16x4 vh;
      vh[0] = f2bf(h0); vh[1] = f2bf(h1); vh[2] = f2bf(h2); vh[3] = f2bf(h3);
      *(u16x4*)&hHi[o] = vh;
    }
  }
}

// ---------------------------------------------------------------------------
// 128x128-tile bf16 GEMM, 2-phase dbuf, 32 KiB LDS, 4 waves, multi-block
// (3-4 blocks/CU — the measured-best regime: 505 TF fc-class, r11).
// Staging pointers and LDS read offsets hoisted out of the K-loop.
// Swizzle: slot g4 ^ ((r>>1)&3), 0 conflicts measured.
// EPI: 0 = +bias +pos -> f32; 1 = +bias -> bf16; 2 = +bias +res -> f32;
//      3 = gelu -> bf16; 4 = +res -> f32.
// ---------------------------------------------------------------------------
template <int EPI>
__global__ __launch_bounds__(256, 4)
void gemm1_kernel(const u16* __restrict__ A, const u16* __restrict__ B,
                  int K, int N, const float* __restrict__ bias,
                  const float* __restrict__ extra, float* __restrict__ outF,
                  u16* __restrict__ outHi) {
  const int tid = threadIdx.x;
  const int lane = tid & 63;
  const int w = tid >> 6;
  const int wm = w >> 1, wn = w & 1;
  const int bm = blockIdx.x * 128, bn = blockIdx.y * 128;
  const int l15 = lane & 15, g4 = lane >> 4;

  __shared__ u16 lds[16384];   // 2 bufs x (A 4096 | B 4096) u16

  f32x4 acc[4][4];
#pragma unroll
  for (int i = 0; i < 4; ++i)
#pragma unroll
    for (int j = 0; j < 4; ++j) acc[i][j] = f32x4{0.f, 0.f, 0.f, 0.f};

  // ---- hoisted staging: chunks c0=tid, c1=tid+256; r=c>>2; slot=(c&3)^((r>>1)&3)
  const int c0 = tid, c1 = tid + 256;
  const int r0 = c0 >> 2, r1 = c1 >> 2;
  const int sg0 = (c0 & 3) ^ ((r0 >> 1) & 3);
  const int sg1 = (c1 & 3) ^ ((r1 >> 1) & 3);
  const u16* pA0 = A + (size_t)(bm + r0) * K + sg0 * 8;
  const u16* pA1 = A + (size_t)(bm + r1) * K + sg1 * 8;
  const u16* pB0 = B + (size_t)(bn + r0) * K + sg0 * 8;
  const u16* pB1 = B + (size_t)(bn + r1) * K + sg1 * 8;
  u16* dA0 = &lds[c0 * 8];
  u16* dA1 = &lds[c1 * 8];
  u16* dB0 = &lds[4096 + c0 * 8];
  u16* dB1 = &lds[4096 + c1 * 8];

  // ---- hoisted ds_read offsets (u16 index)
  int aIdx[4], bIdx[4];
#pragma unroll
  for (int mi = 0; mi < 4; ++mi) {
    int r = wm * 64 + mi * 16 + l15;
    aIdx[mi] = ((r << 2) | (g4 ^ ((r >> 1) & 3))) * 8;
  }
#pragma unroll
  for (int ni = 0; ni < 4; ++ni) {
    int r = wn * 64 + ni * 16 + l15;
    bIdx[ni] = 4096 + (((r << 2) | (g4 ^ ((r >> 1) & 3))) * 8);
  }

  const int nk = K >> 5;
  gll16(pA0, dA0); gll16(pA1, dA1);
  gll16(pB0, dB0); gll16(pB1, dB1);
  pA0 += 32; pA1 += 32; pB0 += 32; pB1 += 32;
  for (int kt = 0; kt < nk; ++kt) {
    const int ab = (kt & 1) * 8192;
    const int nb = ((kt & 1) ^ 1) * 8192;
    __syncthreads();
    if (kt + 1 < nk) {
      gll16(pA0, dA0 + nb); gll16(pA1, dA1 + nb);
      gll16(pB0, dB0 + nb); gll16(pB1, dB1 + nb);
      pA0 += 32; pA1 += 32; pB0 += 32; pB1 += 32;
    }
    s16x8 ah[4], bh[4];
#pragma unroll
    for (int mi = 0; mi < 4; ++mi)
      ah[mi] = *(const s16x8*)&lds[ab + aIdx[mi]];
#pragma unroll
    for (int ni = 0; ni < 4; ++ni)
      bh[ni] = *(const s16x8*)&lds[ab + bIdx[ni]];
#pragma unroll
    for (int mi = 0; mi < 4; ++mi)
#pragma unroll
      for (int ni = 0; ni < 4; ++ni)
        acc[mi][ni] = MFMA_16x16x32_BF16(ah[mi], bh[ni], acc[mi][ni], 0, 0, 0);
  }
  // ---- epilogue: C/D layout row=(lane>>4)*4+reg, col=lane&15 ----
#pragma unroll
  for (int mi = 0; mi < 4; ++mi) {
#pragma unroll
    for (int ni = 0; ni < 4; ++ni) {
      int gc = bn + wn * 64 + ni * 16 + l15;
      float bv = (EPI == 0 || EPI == 1 || EPI == 2) ? bias[gc] : 0.f;
#pragma unroll
      for (int r_ = 0; r_ < 4; ++r_) {
        int gr = bm + wm * 64 + mi * 16 + g4 * 4 + r_;
        float v = acc[mi][ni][r_] + bv;
        size_t o = (size_t)gr * N + gc;
        if (EPI == 0) {
          outF[o] = v + extra[(size_t)(gr & (SEQ - 1)) * EMB + gc];
        } else if (EPI == 1) {
          outHi[o] = f2bf(v);
        } else if (EPI == 2 || EPI == 4) {
          outF[o] = v + extra[o];
        } else {
          float t3 = v + 0.044715f * v * v * v;
          float gl = 0.5f * v * (1.f + tanhf(0.7978845608028654f * t3));
          outHi[o] = f2bf(gl);
        }
      }
    }
  }
}

// ---------------------------------------------------------------------------
// Flash attention fwd, one CH-token chunk (CB batches). grid (SEQ/64, HEADS, CB).
// ---------------------------------------------------------------------------
__global__ __launch_bounds__(256, 2)
void attn_kernel(const u16* __restrict__ qkv, u16* __restrict__ oHi) {
  const int qb = blockIdx.x, h = blockIdx.y, b = blockIdx.z;
  const int tid = threadIdx.x, lane = tid & 63, w = tid >> 6;
  const int l15 = lane & 15, g4 = lane >> 4;

  __shared__ u16 smem[2048 + 2560 + 2048];
  u16* Klds = smem;
  u16* VT   = smem + 2048;
  u16* Pw   = smem + 2048 + 2560 + w * 512;

  const int q0 = qb * 64 + w * 16;
  const size_t base = (size_t)b * SEQ * H3 + (size_t)h * 64;

  s16x8 qf0, qf1;
  {
    const u16* qp = qkv + base + (size_t)(q0 + l15) * H3 + g4 * 8;
    qf0 = *(const s16x8*)qp;
    qf1 = *(const s16x8*)(qp + 32);
  }

  f32x4 of[4];
#pragma unroll
  for (int n = 0; n < 4; ++n) of[n] = f32x4{0.f, 0.f, 0.f, 0.f};
  float mrow[4] = {-1e30f, -1e30f, -1e30f, -1e30f};
  float lrow[4] = {0.f, 0.f, 0.f, 0.f};

  for (int kt = 0; kt < SEQ; kt += 32) {
    {
      int r = tid >> 3;
      int jj = (tid & 7) ^ (r & 7);
      gll16(qkv + base + (size_t)(kt + r) * H3 + EMB + jj * 8, &Klds[tid * 8]);
    }
    {
      int key = tid >> 3, j = tid & 7;
      s16x8 v = *(const s16x8*)(qkv + base + (size_t)(kt + key) * H3 + 2 * EMB + j * 8);
#pragma unroll
      for (int i = 0; i < 8; ++i) VT[(j * 8 + i) * 40 + key] = (u16)v[i];
    }
    __syncthreads();
    const int key0 = l15, key1 = 16 + l15;
    s16x8 kf00 = *(const s16x8*)&Klds[key0 * 64 + (((0 + g4) ^ (key0 & 7)) * 8)];
    s16x8 kf01 = *(const s16x8*)&Klds[key0 * 64 + (((4 + g4) ^ (key0 & 7)) * 8)];
    s16x8 kf10 = *(const s16x8*)&Klds[key1 * 64 + (((0 + g4) ^ (key1 & 7)) * 8)];
    s16x8 kf11 = *(const s16x8*)&Klds[key1 * 64 + (((4 + g4) ^ (key1 & 7)) * 8)];
    f32x4 z = f32x4{0.f, 0.f, 0.f, 0.f};
    f32x4 s0 = MFMA_16x16x32_BF16(qf0, kf00, z, 0, 0, 0);
    s0 = MFMA_16x16x32_BF16(qf1, kf01, s0, 0, 0, 0);
    f32x4 s1 = MFMA_16x16x32_BF16(qf0, kf10, z, 0, 0, 0);
    s1 = MFMA_16x16x32_BF16(qf1, kf11, s1, 0, 0, 0);
#pragma unroll
    for (int r_ = 0; r_ < 4; ++r_) {
      float mx = fmaxf(s0[r_], s1[r_]);
      mx = fmaxf(mx, __shfl_xor(mx, 1));
      mx = fmaxf(mx, __shfl_xor(mx, 2));
      mx = fmaxf(mx, __shfl_xor(mx, 4));
      mx = fmaxf(mx, __shfl_xor(mx, 8));
      float mnew = fmaxf(mrow[r_], mx);
      float alpha = __expf((mrow[r_] - mnew) * 0.125f);
      mrow[r_] = mnew;
      float p0 = __expf((s0[r_] - mnew) * 0.125f);
      float p1 = __expf((s1[r_] - mnew) * 0.125f);
      float ts = p0 + p1;
      ts += __shfl_xor(ts, 1);
      ts += __shfl_xor(ts, 2);
      ts += __shfl_xor(ts, 4);
      ts += __shfl_xor(ts, 8);
      lrow[r_] = lrow[r_] * alpha + ts;
      of[0][r_] *= alpha; of[1][r_] *= alpha;
      of[2][r_] *= alpha; of[3][r_] *= alpha;
      int row = g4 * 4 + r_;
      int sw = (row >> 1) & 3;
      int c0 = (l15 >> 3) ^ sw;
      int c1 = (2 + (l15 >> 3)) ^ sw;
      Pw[(row * 4 + c0) * 8 + (l15 & 7)] = f2bf(p0);
      Pw[(row * 4 + c1) * 8 + (l15 & 7)] = f2bf(p1);
    }
    {
      int pchunk = (l15 << 2) | (g4 ^ ((l15 >> 1) & 3));
      s16x8 pf = *(const s16x8*)&Pw[pchunk * 8];
#pragma unroll
      for (int n = 0; n < 4; ++n) {
        s16x8 vf = *(const s16x8*)&VT[(n * 16 + l15) * 40 + g4 * 8];
        of[n] = MFMA_16x16x32_BF16(pf, vf, of[n], 0, 0, 0);
      }
    }
    __syncthreads();
  }
#pragma unroll
  for (int r_ = 0; r_ < 4; ++r_) {
    float inv = 1.f / lrow[r_];
    int qrow = q0 + g4 * 4 + r_;
    size_t ob = (size_t)(b * SEQ + qrow) * EMB + h * 64;
#pragma unroll
    for (int n = 0; n < 4; ++n)
      oHi[ob + n * 16 + l15] = f2bf(of[n][r_] * inv);
  }
}

// ---------------------------------------------------------------------------
extern "C" void kernel_launch(void* const* d_in, const int* in_sizes, int n_in,
                              void* d_out, int out_size, void* d_ws, size_t ws_size,
                              hipStream_t stream) {
  const float* image1     = (const float*)d_in[0];
  const float* image2     = (const float*)d_in[1];
  const float* text_feat  = (const float*)d_in[2];
  const float* mlp_kernel = (const float*)d_in[3];
  const float* mlp_bias   = (const float*)d_in[4];
  const float* ln1_scale  = (const float*)d_in[5];
  const float* ln1_bias   = (const float*)d_in[6];
  const float* qkv_kernel = (const float*)d_in[7];
  const float* qkv_bias   = (const float*)d_in[8];
  const float* proj_kernel= (const float*)d_in[9];
  const float* proj_bias  = (const float*)d_in[10];
  const float* ln2_scale  = (const float*)d_in[11];
  const float* ln2_bias   = (const float*)d_in[12];
  const float* fc1_kernel = (const float*)d_in[13];
  const float* fc2_kernel = (const float*)d_in[14];
  const float* lnf_scale  = (const float*)d_in[15];
  const float* lnf_bias   = (const float*)d_in[16];

  // ---- workspace layout (bytes), ~178 MiB total
  size_t off = 0;
  auto take = [&](size_t bytes) { size_t o = off; off += (bytes + 255) & ~(size_t)255; return o; };
  char* ws = (char*)d_ws;
  const size_t oX    = take((size_t)TOKENS * EMB * 4);            // 64 MiB residual f32
  const size_t oPos  = take((size_t)SEQ * EMB * 4);               //  2 MiB
  const size_t oSh   = take((size_t)TOKENS * EMB * 2);            // 32 MiB: attn-out | hFull (MLP)
  const size_t oBig  = take((size_t)CH * MLPD * 2);               // 64 MiB: feats | qkv+hC | m-chunk
  const size_t oWbuf = take((size_t)16 * 1024 * 1024);            // 16 MiB weight slots
  if (off > ws_size) {  // diagnostic: absmax ~1e6 next round => ws too small
    fill_kernel<<<(out_size + 255) / 256, 256, 0, stream>>>((float*)d_out, out_size);
    return;
  }

  float* x   = (float*)(ws + oX);
  float* pos = (float*)(ws + oPos);
  u16* shrd  = (u16*)(ws + oSh);
  u16* oA    = shrd;                            // attention output (full), attn phase
  u16* hFull = shrd;                            // LN2 output (full), MLP phase
  u16* big   = (u16*)(ws + oBig);
  u16* hC    = big + (size_t)CH * H3;           // per-chunk LN1 out (attn phase tail)
  u16* wbuf  = (u16*)(ws + oWbuf);
  u16* wq  = wbuf;                              // 6 MiB [3072][1024]
  u16* wp  = wbuf + (size_t)3 * 1024 * 1024;    // 2 MiB [1024][1024]
  u16* wf1 = wbuf;                              // 8 MiB [4096][1024]
  u16* wf2 = wbuf + (size_t)4 * 1024 * 1024;    // 8 MiB [1024][4096]
  u16* w1t = wbuf;                              // 3 MiB [1024][1536]

  pos_kernel<<<SEQ, 256, 0, stream>>>(pos);

  // ---- MLP-in: x = concat(feats) @ W1 + b + pos (gemm1, chunked)
  wtrans_kernel<<<dim3(EMB / 64, K1 / 64), 256, 0, stream>>>(mlp_kernel, w1t, K1, EMB);
  for (int c = 0; c < NCH; ++c) {
    const size_t fo = (size_t)c * CH * 512;
    concat_kernel<<<CH * K1 / 1024, 256, 0, stream>>>(image1 + fo, image2 + fo, text_feat + fo, big);
    gemm1_kernel<0><<<dim3(CH / 128, EMB / 128), 256, 0, stream>>>(
        big, w1t, K1, EMB, mlp_bias, pos, x + (size_t)c * CH * EMB, nullptr);
  }

  for (int i = 0; i < DEPTH; ++i) {
    // ---- attention: qkvT -> wq, projT -> wp (all gemm1 multi-block)
    wtrans_kernel<<<dim3(H3 / 64, EMB / 64), 256, 0, stream>>>(
        qkv_kernel + (size_t)i * EMB * H3, wq, EMB, H3);
    wtrans_kernel<<<dim3(EMB / 64, EMB / 64), 256, 0, stream>>>(
        proj_kernel + (size_t)i * EMB * EMB, wp, EMB, EMB);
    for (int c = 0; c < NCH; ++c) {
      float* xc = x + (size_t)c * CH * EMB;
      ln_kernel<0><<<CH / 4, 256, 0, stream>>>(xc, ln1_scale + i * EMB, ln1_bias + i * EMB,
                                               hC, nullptr);
      gemm1_kernel<1><<<dim3(CH / 128, H3 / 128), 256, 0, stream>>>(
          hC, wq, EMB, H3, qkv_bias + i * H3, nullptr, nullptr, big);
      attn_kernel<<<dim3(SEQ / 64, HEADS, CB), 256, 0, stream>>>(big, oA + (size_t)c * CH * EMB);
    }
    gemm1_kernel<2><<<dim3(TOKENS / 128, EMB / 128), 256, 0, stream>>>(
        oA, wp, EMB, EMB, proj_bias + i * EMB, x, x, nullptr);

    // ---- MLP: hFull = LN2(x) once; fc1 full-N + fc2 full-K per M-chunk (gemm1)
    ln_kernel<0><<<TOKENS / 4, 256, 0, stream>>>(x, ln2_scale + i * EMB, ln2_bias + i * EMB,
                                                 hFull, nullptr);
    wtrans_kernel<<<dim3(MLPD / 64, EMB / 64), 256, 0, stream>>>(
        fc1_kernel + (size_t)i * EMB * MLPD, wf1, EMB, MLPD);
    wtrans_kernel<<<dim3(EMB / 64, MLPD / 64), 256, 0, stream>>>(
        fc2_kernel + (size_t)i * MLPD * EMB, wf2, MLPD, EMB);
    for (int c = 0; c < NCH; ++c) {
      float* xc = x + (size_t)c * CH * EMB;
      gemm1_kernel<3><<<dim3(CH / 128, MLPD / 128), 256, 0, stream>>>(
          hFull + (size_t)c * CH * EMB, wf1, EMB, MLPD, nullptr, nullptr, nullptr, big);
      gemm1_kernel<4><<<dim3(CH / 128, EMB / 128), 256, 0, stream>>>(
          big, wf2, MLPD, EMB, nullptr, xc, xc, nullptr);
    }
  }
  ln_kernel<1><<<TOKENS / 4, 256, 0, stream>>>(x, lnf_scale, lnf_bias,
                                               nullptr, (float*)d_out);
}